// Round 4
// baseline (260.119 us; speedup 1.0000x reference)
//
#include <hip/hip_runtime.h>
#include <hip/hip_bf16.h>

// TrendEncoder: histogram (B=4096, S=200 -> 256 bins) + 256-step LSTM (H=64).
// Round 4: 8-row blocks (2 independent blocks/CU fill latency bubbles) +
// fused-rcp activations with gate-prescaled weights + shfl-based gate
// redistribution so every lane activates exactly 2 real units.
//
// Block = 8 batch rows, 256 threads (4 waves), grid 512 (~2 blocks/CU).
// Wave wv owns gate-col tiles {16wv+64*tt} (tt = gates i,f,g,o).
// MFMA 16x16x32_bf16, M rows 8-15 padded with zero h (wasted, pipe has room).
// Gate prescale folded into W/b: i,f,o rows by -log2e, g rows by 2*log2e, so
//   sigma(x) = rcp(1+exp2(x')) ; tanh(x) = (exp2(x')-1)/(exp2(x')+1)
//   sigma(i)*tanh(g) = (B-1)/((1+A)(B+1))  -> one rcp per product.
// acc rows 2,3 move to quads 2,3 via __shfl_xor(.,32): lane (q,m) activates
// units rows {(q&1)*4 + (q>>1)*2 + 0,1}, col 16wv+m. h (bf16 hi+lo residual)
// round-trips through double-buffered LDS; one __syncthreads per step.

#define B_S     200
#define B_T     256
#define ROWS    8
#define THREADS 256
#define HS      72    // h row stride (bf16 elems)
#define LOG2E   1.4426950408889634f

typedef __attribute__((ext_vector_type(8))) short short8;
typedef __attribute__((ext_vector_type(4))) float float4_t;

__device__ __forceinline__ float load_f(const void* p, int i, int isb) {
    if (isb) {
        unsigned short u = ((const unsigned short*)p)[i];
        return __uint_as_float(((unsigned int)u) << 16);
    }
    return ((const float*)p)[i];
}

__device__ __forceinline__ unsigned short f2bf(float x) {
    unsigned int u = __float_as_uint(x);
    u += 0x7fffu + ((u >> 16) & 1u);          // round-to-nearest-even
    return (unsigned short)(u >> 16);
}

__global__ __launch_bounds__(THREADS, 2)
void trend_encoder_kernel(const void* __restrict__ time_,
                          const int*  __restrict__ length,
                          const void* __restrict__ ptime_,
                          const void* __restrict__ wih_,
                          const void* __restrict__ whh_,
                          const void* __restrict__ bih_,
                          const void* __restrict__ bhh_,
                          void* __restrict__ out_) {
    __shared__ __align__(16) float x_t[B_T * ROWS];               // [t][row], 8 KB
    __shared__ __align__(16) unsigned short h_hi[2][16 * HS];     // rows 8..15 stay 0
    __shared__ __align__(16) unsigned short h_lo[2][16 * HS];
    __shared__ int flag_sh;

    const int tid  = threadIdx.x;
    const int wv   = tid >> 6;        // wave 0..3
    const int lane = tid & 63;
    const int m    = lane & 15;
    const int quad = lane >> 4;
    const int b0   = blockIdx.x * ROWS;

    // ---- dtype probe (wave 0): W_ih ~ U(-0.125,0.125); f32 reinterpreted as
    // bf16 words goes far out of range with overwhelming probability.
    if (tid < 64) {
        unsigned short u = ((const unsigned short*)wih_)[tid];
        float v = __uint_as_float(((unsigned int)u) << 16);
        int bad = !(v > -0.2f && v < 0.2f);
        unsigned long long bm = __ballot(bad);
        if (lane == 0) flag_sh = (bm == 0ULL) ? 1 : 0;
    }
    for (int i = tid; i < B_T * ROWS; i += THREADS) x_t[i] = 0.0f;
    for (int i = tid; i < 2 * 16 * HS; i += THREADS) {
        ((unsigned short*)h_hi)[i] = 0;
        ((unsigned short*)h_lo)[i] = 0;
    }
    __syncthreads();
    const int isb = flag_sh;

    // ---- histogram: pos = trunc((pt - t)*0.25), add at bin 255-pos (transposed)
    for (int e = tid; e < ROWS * B_S; e += THREADS) {
        int row  = e / B_S;
        int s    = e - row * B_S;
        int grow = b0 + row;
        if (s < length[grow]) {
            float pt = load_f(ptime_, grow, isb);
            float tv = load_f(time_, grow * B_S + s, isb);
            int pos = (int)((pt - tv) * 0.25f);
            if (pos >= 0 && pos < B_T)
                atomicAdd(&x_t[(B_T - 1 - pos) * ROWS + row], 1.0f);
        }
    }

    // ---- resident weights, gate-prescaled. tile tt = gate (i,f,g,o),
    // col n = 16wv + 64tt + m.  B-frag: n = lane&15, k = 32c + 8*quad + j.
    const float gsc[4] = {-LOG2E, -LOG2E, 2.0f * LOG2E, -LOG2E};
    short8 bw[4][2];
    float wihv[4], biasv[4];
    #pragma unroll
    for (int tt = 0; tt < 4; ++tt) {
        int n = 16 * wv + 64 * tt + m;
        float s = gsc[tt];
        wihv[tt]  = load_f(wih_, n, isb) * s;
        biasv[tt] = (load_f(bih_, n, isb) + load_f(bhh_, n, isb)) * s;
        #pragma unroll
        for (int c = 0; c < 2; ++c) {
            short8 v;
            #pragma unroll
            for (int j = 0; j < 8; ++j)
                v[j] = (short)f2bf(load_f(whh_, n * 64 + 32 * c + 8 * quad + j, isb) * s);
            bw[tt][c] = v;
        }
    }

    const int aoff = m * HS + 8 * quad;             // A-frag base (elems)
    const int kcol = 16 * wv + m;                   // owned unit column
    const int row0 = (quad & 1) * 4 + (quad >> 1) * 2;  // first owned row
    const int xq   = (quad & 1) * 4;                // in-bounds x row group
    float c2[2] = {0.f, 0.f};
    float h2[2] = {0.f, 0.f};
    __syncthreads();   // histogram + h init + weights visible

    for (int t = 0; t < B_T; ++t) {
        const int p = t & 1;
        const unsigned short* hh = h_hi[p];
        const unsigned short* hl = h_lo[p];
        short8 ahi0 = *(const short8*)&hh[aoff];
        short8 ahi1 = *(const short8*)&hh[aoff + 32];
        short8 alo0 = *(const short8*)&hl[aoff];
        short8 alo1 = *(const short8*)&hl[aoff + 32];
        float4_t xv = *(const float4_t*)&x_t[t * ROWS + xq];

        float4_t acc[4];
        #pragma unroll
        for (int tt = 0; tt < 4; ++tt) {
            float4_t a;
            #pragma unroll
            for (int r = 0; r < 4; ++r) a[r] = fmaf(xv[r], wihv[tt], biasv[tt]);
            a = __builtin_amdgcn_mfma_f32_16x16x32_bf16(ahi0, bw[tt][0], a, 0, 0, 0);
            a = __builtin_amdgcn_mfma_f32_16x16x32_bf16(alo0, bw[tt][0], a, 0, 0, 0);
            a = __builtin_amdgcn_mfma_f32_16x16x32_bf16(ahi1, bw[tt][1], a, 0, 0, 0);
            a = __builtin_amdgcn_mfma_f32_16x16x32_bf16(alo1, bw[tt][1], a, 0, 0, 0);
            acc[tt] = a;
        }

        // redistribute: quads 2,3 take regs 2,3 of quads 0,1 (lane ^ 32)
        float g0[4], g1[4];
        #pragma unroll
        for (int tt = 0; tt < 4; ++tt) {
            float s2 = __shfl_xor(acc[tt][2], 32);
            float s3 = __shfl_xor(acc[tt][3], 32);
            g0[tt] = (quad < 2) ? acc[tt][0] : s2;
            g1[tt] = (quad < 2) ? acc[tt][1] : s3;
        }

        // fused activations for 2 units (rows row0, row0+1; col kcol)
        unsigned short* whi = h_hi[p ^ 1];
        unsigned short* wlo = h_lo[p ^ 1];
        #pragma unroll
        for (int k = 0; k < 2; ++k) {
            float gi = k ? g1[0] : g0[0];
            float gf = k ? g1[1] : g0[1];
            float gg = k ? g1[2] : g0[2];
            float go = k ? g1[3] : g0[3];
            float A = __builtin_amdgcn_exp2f(gi);
            float Bv = __builtin_amdgcn_exp2f(gg);
            float prod = (Bv - 1.0f) * __builtin_amdgcn_rcpf((1.0f + A) * (Bv + 1.0f));
            float F = __builtin_amdgcn_rcpf(1.0f + __builtin_amdgcn_exp2f(gf));
            c2[k] = fmaf(F, c2[k], prod);
            float D = __builtin_amdgcn_exp2f(go);
            float cs = fminf(c2[k] * (2.0f * LOG2E), 126.0f);   // inf guard
            float E = __builtin_amdgcn_exp2f(cs);
            float h = (E - 1.0f) * __builtin_amdgcn_rcpf((1.0f + D) * (E + 1.0f));
            h2[k] = h;
            unsigned short bh = f2bf(h);
            float res = h - __uint_as_float(((unsigned int)bh) << 16);
            whi[(row0 + k) * HS + kcol] = bh;
            wlo[(row0 + k) * HS + kcol] = f2bf(res);
        }
        __syncthreads();   // the only barrier per step
    }

    // ---- epilogue: final h of the 2 owned units
    #pragma unroll
    for (int k = 0; k < 2; ++k) {
        int o = (b0 + row0 + k) * 64 + kcol;
        if (isb) ((__hip_bfloat16*)out_)[o] = __float2bfloat16(h2[k]);
        else     ((float*)out_)[o] = h2[k];
    }
}

extern "C" void kernel_launch(void* const* d_in, const int* in_sizes, int n_in,
                              void* d_out, int out_size, void* d_ws, size_t ws_size,
                              hipStream_t stream) {
    const void* time_  = d_in[0];
    const int*  length = (const int*)d_in[1];
    const void* ptime  = d_in[2];
    const void* wih    = d_in[3];
    const void* whh    = d_in[4];
    const void* bih    = d_in[5];
    const void* bhh    = d_in[6];

    const int B = in_sizes[1];   // 4096
    trend_encoder_kernel<<<dim3(B / ROWS), dim3(THREADS), 0, stream>>>(
        time_, length, ptime, wih, whh, bih, bhh, d_out);
}

// Round 5
// 194.232 us; speedup vs baseline: 1.3392x; 1.3392x over previous
//
#include <hip/hip_runtime.h>
#include <hip/hip_bf16.h>

// TrendEncoder: histogram (B=4096, S=200 -> 256 bins) + 256-step LSTM (H=64).
// Round 5: R3 structure (ROWS=16, 4 waves, in-lane act, 1 barrier/step) with
//  (a) h carried in fp16 (single MFMA path, no hi/lo split): h in (-1,1) has
//      2^-12 RNE error in fp16; output bf16 cast (~2^-9) dominates absmax.
//  (b) fused shared-rcp activations with gate prescale folded into W/b:
//      i,f,o rows by -log2e, g rows by 2*log2e =>
//      c' = [c*(1+A)(B+1) + (1+F)(B-1)] * rcp((1+F)(1+A)(B+1))
//      h  = (E-1) * rcp((1+D)(E+1)),  A,B,F,D,E = exp2(prescaled gates)
//      -> 7 transcendentals + ~17 VALU per unit (trans = quarter-rate, the
//         dominant issue cost).
//
// Block = 16 batch rows, 256 threads (4 waves), grid 256 (1 block/CU).
// Wave wv owns gate-col tiles {16wv+64*tt}, tt = gates i,f,g,o; lane (q,m)
// activates units rows q*4..q*4+3, col 16wv+m entirely in registers.

#define B_S     200
#define B_T     256
#define ROWS    16
#define THREADS 256
#define HS      72    // h row stride (fp16 elems) = 144 B
#define LOG2E   1.4426950408889634f

typedef __attribute__((ext_vector_type(8))) _Float16 half8;
typedef __attribute__((ext_vector_type(4))) float float4_t;

__device__ __forceinline__ float load_f(const void* p, int i, int isb) {
    if (isb) {
        unsigned short u = ((const unsigned short*)p)[i];
        return __uint_as_float(((unsigned int)u) << 16);
    }
    return ((const float*)p)[i];
}

__global__ __launch_bounds__(THREADS)
void trend_encoder_kernel(const void* __restrict__ time_,
                          const int*  __restrict__ length,
                          const void* __restrict__ ptime_,
                          const void* __restrict__ wih_,
                          const void* __restrict__ whh_,
                          const void* __restrict__ bih_,
                          const void* __restrict__ bhh_,
                          void* __restrict__ out_) {
    __shared__ __align__(16) float x_t[B_T * ROWS];            // [t][row], 16 KB
    __shared__ __align__(16) _Float16 h_sh[2][ROWS * HS];      // double-buffered
    __shared__ int flag_sh;

    const int tid  = threadIdx.x;
    const int wv   = tid >> 6;        // wave 0..3
    const int lane = tid & 63;
    const int m    = lane & 15;
    const int quad = lane >> 4;
    const int b0   = blockIdx.x * ROWS;

    // ---- dtype probe (wave 0): W_ih ~ U(-0.125,0.125); f32 reinterpreted as
    // bf16 words goes far out of range with overwhelming probability.
    if (tid < 64) {
        unsigned short u = ((const unsigned short*)wih_)[tid];
        float v = __uint_as_float(((unsigned int)u) << 16);
        int bad = !(v > -0.2f && v < 0.2f);
        unsigned long long bm = __ballot(bad);
        if (lane == 0) flag_sh = (bm == 0ULL) ? 1 : 0;
    }
    for (int i = tid; i < B_T * ROWS; i += THREADS) x_t[i] = 0.0f;
    for (int i = tid; i < ROWS * HS; i += THREADS) h_sh[0][i] = (_Float16)0.0f;
    __syncthreads();
    const int isb = flag_sh;

    // ---- histogram: pos = trunc((pt - t)*0.25), add at bin 255-pos (transposed)
    for (int e = tid; e < ROWS * B_S; e += THREADS) {
        int row  = e / B_S;
        int s    = e - row * B_S;
        int grow = b0 + row;
        if (s < length[grow]) {
            float pt = load_f(ptime_, grow, isb);
            float tv = load_f(time_, grow * B_S + s, isb);
            int pos = (int)((pt - tv) * 0.25f);
            if (pos >= 0 && pos < B_T)
                atomicAdd(&x_t[(B_T - 1 - pos) * ROWS + row], 1.0f);
        }
    }

    // ---- resident weights (fp16, gate-prescaled). tile tt = gate (i,f,g,o),
    // col n = 16wv + 64tt + m.  B-frag: n = lane&15, k = 32c + 8*quad + j.
    // (bf16 weights are exactly representable in fp16.)
    const float gsc[4] = {-LOG2E, -LOG2E, 2.0f * LOG2E, -LOG2E};
    half8 bw[4][2];
    float wihv[4], biasv[4];
    #pragma unroll
    for (int tt = 0; tt < 4; ++tt) {
        int n = 16 * wv + 64 * tt + m;
        float s = gsc[tt];
        wihv[tt]  = load_f(wih_, n, isb) * s;
        biasv[tt] = (load_f(bih_, n, isb) + load_f(bhh_, n, isb)) * s;
        #pragma unroll
        for (int c = 0; c < 2; ++c) {
            half8 v;
            #pragma unroll
            for (int j = 0; j < 8; ++j)
                v[j] = (_Float16)(load_f(whh_, n * 64 + 32 * c + 8 * quad + j, isb) * s);
            bw[tt][c] = v;
        }
    }

    const int aoff = m * HS + 8 * quad;   // A-frag base (elems)
    const int kcol = 16 * wv + m;         // owned unit column
    float creg[4] = {0.f, 0.f, 0.f, 0.f};
    float hreg[4] = {0.f, 0.f, 0.f, 0.f};
    __syncthreads();   // histogram + h init + weights visible

    for (int t = 0; t < B_T; ++t) {
        const int p = t & 1;
        const _Float16* hh = h_sh[p];
        // A fragments (A[m][k], m=lane&15, k=8*quad+j): 2 K-chunks
        half8 a0 = *(const half8*)&hh[aoff];
        half8 a1 = *(const half8*)&hh[aoff + 32];
        // x broadcast: rows quad*4..quad*4+3 of step t, one b128
        float4_t xv = *(const float4_t*)&x_t[t * ROWS + quad * 4];

        float4_t acc[4];
        #pragma unroll
        for (int tt = 0; tt < 4; ++tt) {
            float4_t a;
            #pragma unroll
            for (int r = 0; r < 4; ++r) a[r] = fmaf(xv[r], wihv[tt], biasv[tt]);
            a = __builtin_amdgcn_mfma_f32_16x16x32_f16(a0, bw[tt][0], a, 0, 0, 0);
            a = __builtin_amdgcn_mfma_f32_16x16x32_f16(a1, bw[tt][1], a, 0, 0, 0);
            acc[tt] = a;
        }

        // fused in-lane activation: 4 units (row = quad*4+r, col = kcol)
        _Float16* wb = h_sh[p ^ 1];
        #pragma unroll
        for (int r = 0; r < 4; ++r) {
            float A  = __builtin_amdgcn_exp2f(acc[0][r]);   // exp2(-i*log2e)
            float F  = __builtin_amdgcn_exp2f(acc[1][r]);   // exp2(-f*log2e)
            float Bv = __builtin_amdgcn_exp2f(acc[2][r]);   // exp2(2g*log2e)
            float t1    = (1.0f + A) * (Bv + 1.0f);
            float oneF  = 1.0f + F;
            float numer = fmaf(creg[r], t1, oneF * (Bv - 1.0f));
            float denom = oneF * t1;
            creg[r] = numer * __builtin_amdgcn_rcpf(denom);
            float D  = __builtin_amdgcn_exp2f(acc[3][r]);   // exp2(-o*log2e)
            float cs = fminf(creg[r] * (2.0f * LOG2E), 126.0f);  // inf guard
            float E  = __builtin_amdgcn_exp2f(cs);
            float h  = (E - 1.0f) * __builtin_amdgcn_rcpf((1.0f + D) * (E + 1.0f));
            hreg[r] = h;
            wb[(quad * 4 + r) * HS + kcol] = (_Float16)h;
        }
        __syncthreads();   // the only barrier per step
    }

    // ---- epilogue: final h of the 4 owned units
    #pragma unroll
    for (int r = 0; r < 4; ++r) {
        int o = (b0 + quad * 4 + r) * 64 + kcol;
        if (isb) ((__hip_bfloat16*)out_)[o] = __float2bfloat16(hreg[r]);
        else     ((float*)out_)[o] = hreg[r];
    }
}

extern "C" void kernel_launch(void* const* d_in, const int* in_sizes, int n_in,
                              void* d_out, int out_size, void* d_ws, size_t ws_size,
                              hipStream_t stream) {
    const void* time_  = d_in[0];
    const int*  length = (const int*)d_in[1];
    const void* ptime  = d_in[2];
    const void* wih    = d_in[3];
    const void* whh    = d_in[4];
    const void* bih    = d_in[5];
    const void* bhh    = d_in[6];

    const int B = in_sizes[1];   // 4096
    trend_encoder_kernel<<<dim3(B / ROWS), dim3(THREADS), 0, stream>>>(
        time_, length, ptime, wih, whh, bih, bhh, d_out);
}